// Round 1
// baseline (560.099 us; speedup 1.0000x reference)
//
#include <hip/hip_runtime.h>
#include <math.h>

#define B 64
#define N 1024
#define F 256

// Output layout (floats), concatenated in reference return order:
//   mx [B,F] | nodes [B,N,F] | adj [B,N,N] | num_nodes+1 [B]
#define OUT_MX    0
#define OUT_NODES (B * F)                        // 16384
#define OUT_ADJ   (OUT_NODES + B * N * F)        // 16793600
#define OUT_NN    (OUT_ADJ + B * N * N)          // 83902464

// ---------------------------------------------------------------------------
// Zero the t-accumulator in workspace (ws is poisoned 0xAA each launch).
__global__ void k_zero(float* __restrict__ t) {
    int i = blockIdx.x * 256 + threadIdx.x;
    if (i < B * F) t[i] = 0.0f;
}

// ---------------------------------------------------------------------------
// Updated nodes: wrap (roll up by 1, last row zero) for wrapped batches, then
// scatter x into row nn. Folded: row nn gets x directly (for wrapped batches
// nn == N-1 which is exactly the rolled-in zero row).
// Block = 256 threads -> 4 rows of F=256 floats (64 x float4 per row).
__global__ void k_nodes(const float* __restrict__ x,
                        const float* __restrict__ nodes,
                        const int* __restrict__ num_nodes,
                        float* __restrict__ out) {
    int tid = threadIdx.x;
    int row_in_block = tid >> 6;               // 0..3
    int f4 = (tid & 63) << 2;                  // 0,4,...,252
    long bi = (long)blockIdx.x * 4 + row_in_block;   // row over B*N
    int b = (int)(bi >> 10);
    int i = (int)(bi & (N - 1));
    int nn_in = num_nodes[b];
    bool wrapped = (nn_in == N);
    int nn = wrapped ? (N - 1) : nn_in;
    float4 v;
    if (i == nn) {
        v = *(const float4*)(x + (long)b * F + f4);
    } else {
        // wrapped: i < N-1 here (i == N-1 implies i == nn), so i+1 is in-batch
        long srow = wrapped ? (bi + 1) : bi;
        v = *(const float4*)(nodes + srow * F + f4);
    }
    *(float4*)(out + OUT_NODES + bi * F + f4) = v;
}

// ---------------------------------------------------------------------------
// Updated adj: identity copy for non-wrapped batches; for wrapped batches
// out[i][j] = (i<N-1 && j<N-1) ? adj[i+1][j+1] : 0.
// One block per (b,i) row; 256 threads x float4 = 1024 cols.
__global__ void k_adj(const float* __restrict__ adj,
                      const int* __restrict__ num_nodes,
                      float* __restrict__ out) {
    long bi = blockIdx.x;                      // row over B*N
    int b = (int)(bi >> 10);
    int i = (int)(bi & (N - 1));
    int j = threadIdx.x << 2;                  // 0,4,...,1020
    bool wrapped = (num_nodes[b] == N);
    float4 v;
    const float* base = adj + (long)b * N * N;
    if (!wrapped) {
        v = *(const float4*)(base + (long)i * N + j);
    } else if (i >= N - 1) {
        v = make_float4(0.f, 0.f, 0.f, 0.f);
    } else {
        const float* r = base + (long)(i + 1) * N;
        v.x = (j + 0 < N - 1) ? r[j + 1] : 0.f;
        v.y = (j + 1 < N - 1) ? r[j + 2] : 0.f;
        v.z = (j + 2 < N - 1) ? r[j + 3] : 0.f;
        v.w = (j + 3 < N - 1) ? r[j + 4] : 0.f;
    }
    *(float4*)(out + OUT_ADJ + bi * N + j) = v;
}

// ---------------------------------------------------------------------------
// Partial reduction: t[b,f] = sum_m adjrow[b][m] * nodes_new[b][m][f].
// adjrow for non-wrapped batches is the ORIGINAL adj[b][nn][:] (unchanged by
// the update); for wrapped batches the updated row is all-zero -> skip.
// Grid = B * 16 slices of 64 m-rows. 256 threads, thread owns one f.
#define MCHUNK 64
__global__ void k_partial(const float* __restrict__ adj,
                          const int* __restrict__ num_nodes,
                          const float* __restrict__ out_nodes,
                          float* __restrict__ t) {
    int b = blockIdx.x >> 4;
    int s = blockIdx.x & 15;
    int nn_in = num_nodes[b];
    if (nn_in == N) return;                    // wrapped: adj row nn is zero
    int f = threadIdx.x;
    __shared__ float arow[MCHUNK];
    int m0 = s * MCHUNK;
    if (f < MCHUNK)
        arow[f] = adj[(long)b * N * N + (long)nn_in * N + m0 + f];
    __syncthreads();
    float acc = 0.0f;
    const float* np = out_nodes + ((long)b * N + m0) * F + f;
    #pragma unroll 8
    for (int m = 0; m < MCHUNK; m++)
        acc += arow[m] * np[(long)m * F];
    atomicAdd(&t[b * F + f], acc);
}

// ---------------------------------------------------------------------------
// mx[b,f] = tanh( sum_fp t[b,fp] * W[fp,f] ); also write num_nodes+1 (as f32,
// the harness reads the whole out buffer as float32).
__global__ void k_final(const float* __restrict__ t,
                        const float* __restrict__ W,
                        const int* __restrict__ num_nodes,
                        float* __restrict__ out) {
    int b = blockIdx.x;
    int f = threadIdx.x;
    __shared__ float tl[F];
    tl[f] = t[b * F + f];
    __syncthreads();
    float acc = 0.0f;
    #pragma unroll 8
    for (int fp = 0; fp < F; fp++)
        acc += tl[fp] * W[fp * F + f];
    out[OUT_MX + b * F + f] = tanhf(acc);
    if (f == 0) {
        int nn_in = num_nodes[b];
        int nn = (nn_in == N) ? (N - 1) : nn_in;
        out[OUT_NN + b] = (float)(nn + 1);
    }
}

// ---------------------------------------------------------------------------
extern "C" void kernel_launch(void* const* d_in, const int* in_sizes, int n_in,
                              void* d_out, int out_size, void* d_ws, size_t ws_size,
                              hipStream_t stream) {
    const float* x         = (const float*)d_in[0];
    const float* nodes     = (const float*)d_in[1];
    const float* adj       = (const float*)d_in[2];
    const int*   num_nodes = (const int*)d_in[3];
    const float* W         = (const float*)d_in[4];
    float* out = (float*)d_out;
    float* t   = (float*)d_ws;   // B*F floats

    hipLaunchKernelGGL(k_zero,    dim3((B * F) / 256), dim3(256), 0, stream, t);
    hipLaunchKernelGGL(k_nodes,   dim3((B * N) / 4),   dim3(256), 0, stream,
                       x, nodes, num_nodes, out);
    hipLaunchKernelGGL(k_adj,     dim3(B * N),         dim3(256), 0, stream,
                       adj, num_nodes, out);
    hipLaunchKernelGGL(k_partial, dim3(B * 16),        dim3(256), 0, stream,
                       adj, num_nodes, out + OUT_NODES, t);
    hipLaunchKernelGGL(k_final,   dim3(B),             dim3(256), 0, stream,
                       t, W, num_nodes, out);
}

// Round 2
// 559.453 us; speedup vs baseline: 1.0012x; 1.0012x over previous
//
#include <hip/hip_runtime.h>
#include <math.h>

#define B 64
#define N 1024
#define F 256

// Output layout (floats), concatenated in reference return order:
//   mx [B,F] | nodes [B,N,F] | adj [B,N,N] | num_nodes+1 [B]
#define OUT_MX    0
#define OUT_NODES (B * F)                        // 16384
#define OUT_ADJ   (OUT_NODES + B * N * F)        // 16793600
#define OUT_NN    (OUT_ADJ + B * N * N)          // 83902464

#define NODES_BLOCKS (B * 16)                    // 1024: one block = 64-row slice
#define ADJ_BLOCKS   (B * N / 4)                 // 16384: one block = 4 adj rows

// ---------------------------------------------------------------------------
// Fused main kernel.
// Branch A (blk < NODES_BLOCKS): write updated nodes (wrap-roll + scatter x)
//   for a 64-row slice of batch b, and simultaneously accumulate the partial
//   reduction t_partial = sum_m adj[b][nn][m] * nodes_new[b][m][:] for those
//   rows. Partials land in ws (no atomics, no zero-init needed).
//   For wrapped batches (num_nodes==N) the updated adj row nn is all-zero,
//   so the partial is exactly 0.
// Branch B: pure adj update copy, 4 rows of 1024 floats per block, float4.
__global__ void k_main(const float* __restrict__ x,
                       const float* __restrict__ nodes,
                       const float* __restrict__ adj,
                       const int* __restrict__ num_nodes,
                       float* __restrict__ out,
                       float* __restrict__ partial) {
    __shared__ float arow[64];
    int blk = blockIdx.x;
    int t = threadIdx.x;

    if (blk < NODES_BLOCKS) {
        int b = blk >> 4;
        int s = blk & 15;
        int m0 = s << 6;                       // first row of the 64-row slice
        int nn_in = num_nodes[b];
        bool wrapped = (nn_in == N);
        int nn = wrapped ? (N - 1) : nn_in;
        // Stage the adj row segment (original adj row nn is unchanged by the
        // update when !wrapped; when wrapped the updated row is all-zero).
        if (t < 64)
            arow[t] = wrapped ? 0.0f
                              : adj[((long)b * N + nn) * N + m0 + t];
        __syncthreads();

        int g  = t >> 6;                       // wave id 0..3 (row group)
        int f4 = (t & 63) << 2;                // feature column 0,4,...,252
        const float* xrow   = x + (long)b * F;
        const float* innode = nodes + (long)b * N * F;
        float* onode = out + OUT_NODES + ((long)b * N + m0) * F;
        float4 acc = make_float4(0.f, 0.f, 0.f, 0.f);
        #pragma unroll
        for (int it = 0; it < 16; ++it) {
            int r = (it << 2) + g;             // row within slice, per-wave uniform
            int row = m0 + r;
            float4 v;
            if (row == nn) {
                v = *(const float4*)(xrow + f4);
            } else {
                // wrapped: row < N-1 here (row==N-1 implies row==nn)
                int srow = wrapped ? (row + 1) : row;
                v = *(const float4*)(innode + (long)srow * F + f4);
            }
            *(float4*)(onode + (long)r * F + f4) = v;
            float a = arow[r];                 // wave-uniform LDS broadcast
            acc.x += a * v.x; acc.y += a * v.y;
            acc.z += a * v.z; acc.w += a * v.w;
        }
        // partial slot p = b*64 + s*4 + g  (64 partials per batch)
        *(float4*)(partial + ((long)(b << 6) + (s << 2) + g) * F + f4) = acc;
    } else {
        long rb = (long)(blk - NODES_BLOCKS) << 2;   // first (b,i) row
        int j = t << 2;                              // column 0,4,...,1020
        #pragma unroll
        for (int k = 0; k < 4; ++k) {
            long bi = rb + k;
            int b = (int)(bi >> 10);
            int i = (int)(bi & (N - 1));
            bool wrapped = (num_nodes[b] == N);
            const float* base = adj + (long)b * N * N;
            float4 v;
            if (!wrapped) {
                v = *(const float4*)(base + (long)i * N + j);
            } else if (i >= N - 1) {
                v = make_float4(0.f, 0.f, 0.f, 0.f);
            } else {
                const float* r2 = base + (long)(i + 1) * N;
                v.x = (j + 0 < N - 1) ? r2[j + 1] : 0.f;
                v.y = (j + 1 < N - 1) ? r2[j + 2] : 0.f;
                v.z = (j + 2 < N - 1) ? r2[j + 3] : 0.f;
                v.w = (j + 3 < N - 1) ? r2[j + 4] : 0.f;
            }
            *(float4*)(out + OUT_ADJ + bi * N + j) = v;
        }
    }
}

// ---------------------------------------------------------------------------
// Finalize: t[b,f] = sum of 64 partials; mx = tanh(t @ W); num_nodes+1.
__global__ void k_final(const float* __restrict__ partial,
                        const float* __restrict__ W,
                        const int* __restrict__ num_nodes,
                        float* __restrict__ out) {
    int b = blockIdx.x;
    int f = threadIdx.x;
    __shared__ float tl[F];
    float s = 0.0f;
    const float* p = partial + ((long)b << 6) * F + f;
    #pragma unroll 8
    for (int k = 0; k < 64; ++k)
        s += p[(long)k * F];
    tl[f] = s;
    __syncthreads();
    float acc = 0.0f;
    #pragma unroll 8
    for (int fp = 0; fp < F; ++fp)
        acc += tl[fp] * W[fp * F + f];         // tl[fp]: uniform broadcast
    out[OUT_MX + b * F + f] = tanhf(acc);
    if (f == 0) {
        int nn_in = num_nodes[b];
        int nn = (nn_in == N) ? (N - 1) : nn_in;
        out[OUT_NN + b] = (float)(nn + 1);
    }
}

// ---------------------------------------------------------------------------
extern "C" void kernel_launch(void* const* d_in, const int* in_sizes, int n_in,
                              void* d_out, int out_size, void* d_ws, size_t ws_size,
                              hipStream_t stream) {
    const float* x         = (const float*)d_in[0];
    const float* nodes     = (const float*)d_in[1];
    const float* adj       = (const float*)d_in[2];
    const int*   num_nodes = (const int*)d_in[3];
    const float* W         = (const float*)d_in[4];
    float* out     = (float*)d_out;
    float* partial = (float*)d_ws;             // B*64*F floats = 4 MB

    hipLaunchKernelGGL(k_main, dim3(NODES_BLOCKS + ADJ_BLOCKS), dim3(256), 0,
                       stream, x, nodes, adj, num_nodes, out, partial);
    hipLaunchKernelGGL(k_final, dim3(B), dim3(256), 0, stream,
                       partial, W, num_nodes, out);
}